// Round 1
// 442.778 us; speedup vs baseline: 1.0019x; 1.0019x over previous
//
#include <hip/hip_runtime.h>

#define N_NODES 100000
#define N_EDGES 3200000
#define HD      32
#define NLAYERS 4
#define NGRAPHS 1000
#define BN_EPS  1e-5f
#define BSHIFT  9                         // 512-node buckets
#define NBUCK   ((N_NODES + 511) >> 9)    // 196
#define PCHUNK  8192                      // edges per partition block
#define NPB     ((N_EDGES + PCHUNK - 1) / PCHUNK)   // 391
#define ZBLOCKS ((NGRAPHS * HD + 255) / 256)        // 125

typedef _Float16 f16;
typedef _Float16 f16x8 __attribute__((ext_vector_type(8)));
typedef float    f32x4 __attribute__((ext_vector_type(4)));
typedef int      i32x4 __attribute__((ext_vector_type(4)));
typedef unsigned int  u32x2 __attribute__((ext_vector_type(2)));
typedef unsigned char uc8 __attribute__((ext_vector_type(8)));

// ---------------- phist + zero stats/pooled (encoder removed: rank-2 layer 0) --
__global__ __launch_bounds__(256) void k_encphist(
    const int* __restrict__ ei, float* __restrict__ stats,
    float* __restrict__ pooled, int* __restrict__ pcnt)
{
    __shared__ int hist[256];
    int bb = blockIdx.x, t = threadIdx.x;
    if (bb < NPB) {                                  // ---- phist part
        hist[t] = 0;
        __syncthreads();
        int base4 = bb * (PCHUNK / 4);
        int n4 = min(PCHUNK / 4, N_EDGES / 4 - base4);
        const i32x4* d4 = (const i32x4*)(ei + N_EDGES);
        for (int k = t; k < n4; k += 256) {
            i32x4 d = __builtin_nontemporal_load(d4 + base4 + k);
            atomicAdd(&hist[d.x >> BSHIFT], 1);
            atomicAdd(&hist[d.y >> BSHIFT], 1);
            atomicAdd(&hist[d.z >> BSHIFT], 1);
            atomicAdd(&hist[d.w >> BSHIFT], 1);
        }
        __syncthreads();
        pcnt[t * NPB + bb] = hist[t];
    } else {                                         // ---- zeroing part
        int gid = (bb - NPB) * 256 + t;
        if (gid < NLAYERS * 64)   stats[gid]  = 0.f;
        if (gid < NGRAPHS * HD)   pooled[gid] = 0.f;
    }
}

// per-bucket scan of per-block counts (in place) + bucket totals
__global__ __launch_bounds__(512) void k_pscanA(int* __restrict__ pcnt,
                                                int* __restrict__ btot)
{
    __shared__ int sc[2][512];
    int t = threadIdx.x, b = blockIdx.x;
    int base = b * NPB;
    int v = (t < NPB) ? pcnt[base + t] : 0;
    int pp = 0;
    sc[0][t] = v;
    __syncthreads();
    for (int st = 1; st < 512; st <<= 1) {
        int x = sc[pp][t];
        if (t >= st) x += sc[pp][t - st];
        sc[pp ^ 1][t] = x;
        pp ^= 1;
        __syncthreads();
    }
    int incl = sc[pp][t];
    if (t < NPB) pcnt[base + t] = incl - v;
    if (t == NPB - 1) btot[b] = incl;
}

// scatter packed edges (src<<9 | dstLocal) into dst-bucket regions
__global__ __launch_bounds__(256) void k_pscatter(const int* __restrict__ ei,
                                                  const int* __restrict__ pcnt,
                                                  const int* __restrict__ btot,
                                                  unsigned int* __restrict__ ebuf)
{
    __shared__ int sb[2][256];
    __shared__ int lcur[256];
    int t = threadIdx.x, blk = blockIdx.x;
    sb[0][t] = (t < NBUCK) ? btot[t] : 0;
    __syncthreads();
    int pp = 0;
    for (int st = 1; st < 256; st <<= 1) {
        int v = sb[pp][t];
        if (t >= st) v += sb[pp][t - st];
        sb[pp ^ 1][t] = v;
        pp ^= 1;
        __syncthreads();
    }
    int bexcl = (t == 0) ? 0 : sb[pp][t - 1];
    lcur[t] = pcnt[t * NPB + blk] + bexcl;
    __syncthreads();
    int base4 = blk * (PCHUNK / 4);
    int n4 = min(PCHUNK / 4, N_EDGES / 4 - base4);
    const i32x4* s4 = (const i32x4*)ei;
    const i32x4* d4 = (const i32x4*)(ei + N_EDGES);
    for (int k = t; k < n4; k += 256) {
        i32x4 s = __builtin_nontemporal_load(s4 + base4 + k);
        i32x4 d = __builtin_nontemporal_load(d4 + base4 + k);
        int pos;
        pos = atomicAdd(&lcur[d.x >> BSHIFT], 1);
        ebuf[pos] = ((unsigned)s.x << BSHIFT) | (unsigned)(d.x & 511);
        pos = atomicAdd(&lcur[d.y >> BSHIFT], 1);
        ebuf[pos] = ((unsigned)s.y << BSHIFT) | (unsigned)(d.y & 511);
        pos = atomicAdd(&lcur[d.z >> BSHIFT], 1);
        ebuf[pos] = ((unsigned)s.z << BSHIFT) | (unsigned)(d.z & 511);
        pos = atomicAdd(&lcur[d.w >> BSHIFT], 1);
        ebuf[pos] = ((unsigned)s.w << BSHIFT) | (unsigned)(d.w & 511);
    }
}

// per-bucket local sort -> final CSR + off[] (bucket scan inline)
__global__ __launch_bounds__(512) void k_bfinal(const unsigned int* __restrict__ ebuf,
                                                const int* __restrict__ btot,
                                                int* __restrict__ off,
                                                int* __restrict__ csr)
{
    __shared__ int sb[2][256];
    __shared__ int cnt[512], scanbuf[2][512], cur[512];
    int tid = threadIdx.x, b = blockIdx.x;
    if (tid < 256) sb[0][tid] = (tid < NBUCK) ? btot[tid] : 0;
    __syncthreads();
    int pp = 0;
    for (int st = 1; st < 256; st <<= 1) {
        if (tid < 256) {
            int v = sb[pp][tid];
            if (tid >= st) v += sb[pp][tid - st];
            sb[pp ^ 1][tid] = v;
        }
        pp ^= 1;
        __syncthreads();
    }
    int base = (b == 0) ? 0 : sb[pp][b - 1];
    int nE = sb[pp][b] - base;
    if (b == NBUCK - 1 && tid == 0) off[N_NODES] = sb[pp][NBUCK - 1];
    cnt[tid] = 0;
    __syncthreads();
    for (int e = tid; e < nE; e += 512)
        atomicAdd(&cnt[ebuf[base + e] & 511], 1);
    __syncthreads();
    int p2 = 0;
    scanbuf[0][tid] = cnt[tid];
    __syncthreads();
    for (int st = 1; st < 512; st <<= 1) {
        int v = scanbuf[p2][tid];
        if (tid >= st) v += scanbuf[p2][tid - st];
        scanbuf[p2 ^ 1][tid] = v;
        p2 ^= 1;
        __syncthreads();
    }
    int excl = scanbuf[p2][tid] - cnt[tid];
    cur[tid] = excl;
    int gnode = (b << BSHIFT) + tid;
    if (gnode < N_NODES) off[gnode] = base + excl;
    __syncthreads();
    for (int e = tid; e < nE; e += 512) {
        unsigned int p = ebuf[base + e];
        int pos = atomicAdd(&cur[p & 511], 1);
        csr[base + pos] = (int)(p >> BSHIFT);
    }
}

// ---------------- fused GIN layer: agg (+dequant) -> in-wave transpose ->
//                  MFMA MLP -> z2 + BN stats.  One 16-node tile per wave.
// Layer 0 uses the rank-2 identity: z1_i = u_i*W_enc + d_i*b_enc with
// u_i = (1+eps)x_i + sum_j x_j,  d_i = (1+eps) + deg_i  (exact, no int8).
__global__ __launch_bounds__(256) void k_fused(
    const unsigned char* __restrict__ hq, const float* __restrict__ x,
    const int* __restrict__ off, const int* __restrict__ csr,
    const float* __restrict__ epsArr, const float* __restrict__ gamma,
    const float* __restrict__ beta, const float* __restrict__ W_enc,
    const float* __restrict__ b_enc, const float* __restrict__ W1,
    const float* __restrict__ b1, const float* __restrict__ W2,
    const float* __restrict__ b2, f16* __restrict__ z2out,
    float* __restrict__ stats, int layer)
{
    __shared__ f16 AT[4][16][5][8];      // [wave][node][group(pad 4->5)][8ch]
    __shared__ float T[4][16 * 36];
    __shared__ float redS[4][32], redQ[4][32];
    int tid = threadIdx.x, wave = tid >> 6, lane = tid & 63;
    int col = lane & 15, quad = lane >> 4;
    int unit = tid >> 2, li = tid & 3, ul = unit & 15;
    int node = blockIdx.x * 64 + unit;
    bool valid = node < N_NODES;         // wave-uniform: 16 | N_NODES
    int co = li * 8;

    f16x8 r;
    #pragma unroll
    for (int k = 0; k < 8; ++k) r[k] = (f16)0.f;

    if (valid) {
        if (layer == 0) {                // ---- rank-2 scalar aggregation
            int j0 = off[node], jend = off[node + 1];
            float S = 0.f;
            for (int j = j0 + li; j < jend; j += 4) S += x[csr[j]];
            S += __shfl_xor(S, 1);
            S += __shfl_xor(S, 2);
            float oneEps = 1.f + epsArr[0];
            float u  = oneEps * x[node] + S;
            float dv = oneEps + (float)(jend - j0);
            #pragma unroll
            for (int k = 0; k < 8; ++k)
                r[k] = (f16)(fmaf(u, W_enc[co + k], dv * b_enc[co + k]));
        } else {                         // ---- int8 gather aggregation
            float dq_s[8];
            #pragma unroll
            for (int k = 0; k < 8; ++k) {
                int ch = co + k;
                float g  = gamma[(layer - 1) * 32 + ch];
                float bb = beta[(layer - 1) * 32 + ch];
                float vmax = fmaxf(bb + 5.5f * fabsf(g), 0.f);
                dq_s[k] = fmaxf(vmax, 1e-6f) / 255.f;
            }
            float oneEps = 1.f + epsArr[layer];
            const unsigned MASK = 0x00FF00FFu;
            int j = off[node], jend = off[node + 1];
            unsigned a0 = 0, a1 = 0, a2 = 0, a3 = 0;
            auto accum = [&](u32x2 v) {
                a0 += v.x & MASK; a1 += (v.x >> 8) & MASK;
                a2 += v.y & MASK; a3 += (v.y >> 8) & MASK;
            };
            while (j < jend && (j & 3))
                accum(*(const u32x2*)(hq + csr[j++] * 32 + co));
            int n8 = (jend - j) >> 3;
            for (int it = 0; it < n8; ++it) {        // 8 rows in flight
                i32x4 q0 = __builtin_nontemporal_load((const i32x4*)(csr + j));
                i32x4 q1 = __builtin_nontemporal_load((const i32x4*)(csr + j + 4));
                u32x2 g0 = *(const u32x2*)(hq + q0.x * 32 + co);
                u32x2 g1 = *(const u32x2*)(hq + q0.y * 32 + co);
                u32x2 g2 = *(const u32x2*)(hq + q0.z * 32 + co);
                u32x2 g3 = *(const u32x2*)(hq + q0.w * 32 + co);
                u32x2 g4 = *(const u32x2*)(hq + q1.x * 32 + co);
                u32x2 g5 = *(const u32x2*)(hq + q1.y * 32 + co);
                u32x2 g6 = *(const u32x2*)(hq + q1.z * 32 + co);
                u32x2 g7 = *(const u32x2*)(hq + q1.w * 32 + co);
                accum(g0); accum(g1); accum(g2); accum(g3);
                accum(g4); accum(g5); accum(g6); accum(g7);
                j += 8;
            }
            if (jend - j >= 4) {
                i32x4 q0 = *(const i32x4*)(csr + j);
                accum(*(const u32x2*)(hq + q0.x * 32 + co));
                accum(*(const u32x2*)(hq + q0.y * 32 + co));
                accum(*(const u32x2*)(hq + q0.z * 32 + co));
                accum(*(const u32x2*)(hq + q0.w * 32 + co));
                j += 4;
            }
            while (j < jend)
                accum(*(const u32x2*)(hq + csr[j++] * 32 + co));

            u32x2 gs = *(const u32x2*)(hq + node * 32 + co);  // self row
            float F[8];
            F[0] = (float)(a0 & 0xFFFF); F[2] = (float)(a0 >> 16);
            F[1] = (float)(a1 & 0xFFFF); F[3] = (float)(a1 >> 16);
            F[4] = (float)(a2 & 0xFFFF); F[6] = (float)(a2 >> 16);
            F[5] = (float)(a3 & 0xFFFF); F[7] = (float)(a3 >> 16);
            #pragma unroll
            for (int k = 0; k < 4; ++k) {
                float qsl = (float)((gs.x >> (8 * k)) & 255u);
                float qsh = (float)((gs.y >> (8 * k)) & 255u);
                r[k]     = (f16)(dq_s[k]     * (F[k]     + oneEps * qsl));
                r[k + 4] = (f16)(dq_s[k + 4] * (F[k + 4] + oneEps * qsh));
            }
        }
    }

    // in-wave transpose to MFMA A-fragment layout (wave-synchronous LDS)
    if (valid) *(f16x8*)&AT[wave][ul][li][0] = r;

    float sA = 0.f, qA = 0.f, sB = 0.f, qB = 0.f;
    if (valid) {
        f16x8 a = *(const f16x8*)&AT[wave][col][quad][0];
        const float* W1l = W1 + layer * 1024;
        const float* W2l = W2 + layer * 1024;
        f16x8 w1a, w1b, w2a, w2b;                    // B[k=quad*8+j][n=col(+16)]
        #pragma unroll
        for (int jj = 0; jj < 8; ++jj) {
            int k = quad * 8 + jj;
            w1a[jj] = (f16)W1l[k * 32 + col];
            w1b[jj] = (f16)W1l[k * 32 + col + 16];
            w2a[jj] = (f16)W2l[k * 32 + col];
            w2b[jj] = (f16)W2l[k * 32 + col + 16];
        }
        float b1a = b1[layer * 32 + col], b1b = b1[layer * 32 + col + 16];
        float b2a = b2[layer * 32 + col], b2b = b2[layer * 32 + col + 16];
        f32x4 bias1a = {b1a, b1a, b1a, b1a}, bias1b = {b1b, b1b, b1b, b1b};
        f32x4 bias2a = {b2a, b2a, b2a, b2a}, bias2b = {b2b, b2b, b2b, b2b};
        float* Tw = T[wave];

        f32x4 m0 = __builtin_amdgcn_mfma_f32_16x16x32_f16(a, w1a, bias1a, 0, 0, 0);
        f32x4 m1 = __builtin_amdgcn_mfma_f32_16x16x32_f16(a, w1b, bias1b, 0, 0, 0);
        #pragma unroll
        for (int rr = 0; rr < 4; ++rr) {             // relu + D-layout -> LDS
            int row = quad * 4 + rr;
            Tw[row * 36 + col]      = fmaxf(m0[rr], 0.f);
            Tw[row * 36 + col + 16] = fmaxf(m1[rr], 0.f);
        }
        f32x4 t0 = *(const f32x4*)(Tw + col * 36 + quad * 8);     // wave-sync
        f32x4 t1 = *(const f32x4*)(Tw + col * 36 + quad * 8 + 4);
        f16x8 a2;
        #pragma unroll
        for (int k = 0; k < 4; ++k) { a2[k] = (f16)t0[k]; a2[k + 4] = (f16)t1[k]; }
        f32x4 z0 = __builtin_amdgcn_mfma_f32_16x16x32_f16(a2, w2a, bias2a, 0, 0, 0);
        f32x4 zb = __builtin_amdgcn_mfma_f32_16x16x32_f16(a2, w2b, bias2b, 0, 0, 0);
        int nb = blockIdx.x * 64 + wave * 16;
        #pragma unroll
        for (int rr = 0; rr < 4; ++rr) {
            int n2 = nb + quad * 4 + rr;
            z2out[n2 * 32 + col]      = (f16)z0[rr];
            z2out[n2 * 32 + col + 16] = (f16)zb[rr];
            sA += z0[rr]; qA += z0[rr] * z0[rr];
            sB += zb[rr]; qB += zb[rr] * zb[rr];
        }
    }

    sA += __shfl_xor(sA, 16); sA += __shfl_xor(sA, 32);
    qA += __shfl_xor(qA, 16); qA += __shfl_xor(qA, 32);
    sB += __shfl_xor(sB, 16); sB += __shfl_xor(sB, 32);
    qB += __shfl_xor(qB, 16); qB += __shfl_xor(qB, 32);
    if (lane < 16) {
        redS[wave][col] = sA; redS[wave][col + 16] = sB;
        redQ[wave][col] = qA; redQ[wave][col + 16] = qB;
    }
    __syncthreads();
    if (tid < 64) {
        int sel = tid >> 5, cc = tid & 31;
        float s = 0.f;
        #pragma unroll
        for (int w = 0; w < 4; ++w) s += sel ? redQ[w][cc] : redS[w][cc];
        atomicAdd(&stats[layer * 64 + sel * 32 + cc], s);
    }
}

// ---------------- quantize: hq = uint8( relu(BN(z2)) / s )  -------------------
__global__ __launch_bounds__(256) void k_quant(
    const f16* __restrict__ z2, const float* __restrict__ stats,
    const float* __restrict__ gamma, const float* __restrict__ beta,
    unsigned char* __restrict__ hq, int layer)
{
    int idx = blockIdx.x * 256 + threadIdx.x;        // over N*4 (8 ch each)
    if (idx >= N_NODES * 4) return;
    int c0 = (idx & 3) * 8;
    const float invN = 1.0f / (float)N_NODES;
    float bnsc[8], bnsh[8], inv_s[8];
    #pragma unroll
    for (int k = 0; k < 8; ++k) {
        int ch = c0 + k;
        float g = gamma[layer * 32 + ch], bb = beta[layer * 32 + ch];
        float mu  = stats[layer * 64 + ch] * invN;
        float var = stats[layer * 64 + 32 + ch] * invN - mu * mu;
        float sc = g * rsqrtf(var + BN_EPS);
        bnsc[k] = sc;
        bnsh[k] = bb - mu * sc;
        float vmax = fmaxf(bb + 5.5f * fabsf(g), 0.f);
        inv_s[k] = 255.f / fmaxf(vmax, 1e-6f);       // matches k_fused dq_s
    }
    f16x8 z = *(const f16x8*)(z2 + (size_t)idx * 8);
    uc8 r;
    #pragma unroll
    for (int k = 0; k < 8; ++k) {
        float v = fmaxf(fmaf((float)z[k], bnsc[k], bnsh[k]), 0.f);
        int q = (int)(fminf(v * inv_s[k], 255.f) + 0.5f);
        r[k] = (unsigned char)q;
    }
    __builtin_nontemporal_store(r, (uc8*)(hq + (size_t)idx * 8));
}

// ---------------- global_add_pool with inline BN(3)+ReLU -----------------------
__global__ __launch_bounds__(256) void k_pool(const f16* __restrict__ z2,
                                              const int* __restrict__ batch,
                                              const float* __restrict__ stats,
                                              const float* __restrict__ gamma,
                                              const float* __restrict__ beta,
                                              float* __restrict__ pooled)
{
    int c = threadIdx.x & 31, slot = threadIdx.x >> 5;
    const float invN = 1.0f / (float)N_NODES;
    float mu  = stats[3 * 64 + c] * invN;
    float var = stats[3 * 64 + 32 + c] * invN - mu * mu;
    float sc = gamma[3 * 32 + c] * rsqrtf(var + BN_EPS);
    float sh = beta[3 * 32 + c] - mu * sc;
    int start = blockIdx.x * 256 + slot * 32;
    if (start >= N_NODES) return;
    int end = min(start + 32, N_NODES);
    int cur = batch[start]; float acc = 0.f;
    for (int i = start; i < end; ++i) {
        int g = batch[i];
        if (g != cur) { atomicAdd(&pooled[cur * HD + c], acc); acc = 0.f; cur = g; }
        acc += fmaxf(fmaf((float)z2[i * 32 + c], sc, sh), 0.f);
    }
    atomicAdd(&pooled[cur * HD + c], acc);
}

// ---------------- classifier ---------------------------------------------------
__global__ __launch_bounds__(256) void k_cls(const float* __restrict__ pooled,
                                             const float* __restrict__ Wc,
                                             const float* __restrict__ bc,
                                             float* __restrict__ out)
{
    int gid = blockIdx.x * 256 + threadIdx.x;
    if (gid >= NGRAPHS * 2) return;
    int g = gid >> 1, c = gid & 1;
    float s = bc[c];
    #pragma unroll
    for (int k = 0; k < 32; ++k) s = fmaf(pooled[g * 32 + k], Wc[k * 2 + c], s);
    out[gid] = s;
}

extern "C" void kernel_launch(void* const* d_in, const int* in_sizes, int n_in,
                              void* d_out, int out_size, void* d_ws, size_t ws_size,
                              hipStream_t stream)
{
    const float* x      = (const float*)d_in[0];
    const int*   ei     = (const int*)d_in[1];
    const int*   batch  = (const int*)d_in[2];
    const float* W_enc  = (const float*)d_in[3];
    const float* b_enc  = (const float*)d_in[4];
    const float* epsArr = (const float*)d_in[5];
    const float* W1     = (const float*)d_in[6];
    const float* b1     = (const float*)d_in[7];
    const float* W2     = (const float*)d_in[8];
    const float* b2     = (const float*)d_in[9];
    const float* gamma  = (const float*)d_in[10];
    const float* beta   = (const float*)d_in[11];
    const float* Wc     = (const float*)d_in[12];
    const float* bc     = (const float*)d_in[13];
    float* out = (float*)d_out;

    char* ws = (char*)d_ws;
    size_t o = 0;
    auto alloc = [&](size_t bytes) {
        char* p = ws + o;
        o += (bytes + 255) & ~(size_t)255;
        return p;
    };
    unsigned char* hq = (unsigned char*)alloc((size_t)N_NODES * 32);  // 3.2 MB
    f16*   z2     = (f16*) alloc((size_t)N_NODES * 32 * 2);    // 6.4 MB [node][32]
    int*   csr    = (int*) alloc((size_t)N_EDGES * 4);         // 12.8 MB
    unsigned int* ebuf = (unsigned int*)alloc((size_t)N_EDGES * 4);  // 12.8 MB
    int*   offA   = (int*) alloc((size_t)(N_NODES + 1) * 4);
    int*   pcnt   = (int*) alloc((size_t)256 * NPB * 4);       // 0.4 MB
    int*   btot   = (int*) alloc(1024);
    float* stats  = (float*)alloc(NLAYERS * 64 * 4);
    float* pooled = (float*)alloc((size_t)NGRAPHS * HD * 4);

    k_encphist<<<NPB + ZBLOCKS, 256, 0, stream>>>(ei, stats, pooled, pcnt);
    k_pscanA  <<<NBUCK, 512, 0, stream>>>(pcnt, btot);
    k_pscatter<<<NPB, 256, 0, stream>>>(ei, pcnt, btot, ebuf);
    k_bfinal  <<<NBUCK, 512, 0, stream>>>(ebuf, btot, offA, csr);

    for (int l = 0; l < NLAYERS; ++l) {
        k_fused<<<(N_NODES + 63) / 64, 256, 0, stream>>>(
            hq, x, offA, csr, epsArr, gamma, beta, W_enc, b_enc,
            W1, b1, W2, b2, z2, stats, l);
        if (l < NLAYERS - 1)
            k_quant<<<(N_NODES * 4 + 255) / 256, 256, 0, stream>>>(z2, stats,
                                                                   gamma, beta,
                                                                   hq, l);
    }
    k_pool<<<(N_NODES + 255) / 256, 256, 0, stream>>>(z2, batch, stats,
                                                      gamma, beta, pooled);
    k_cls <<<8, 256, 0, stream>>>(pooled, Wc, bc, out);
}